// Round 2
// baseline (6368.860 us; speedup 1.0000x reference)
//
#include <hip/hip_runtime.h>

#define HD 128        // NUM_HEADS*OUT_DIM == IN_DIM
#define NHEADS 4
#define GROWS 128     // rows per gemm block
#define WT_PITCH 132  // padded LDS pitch for transposed weights
#define FS_PITCH 132  // padded LDS pitch for feat tile

__device__ __forceinline__ unsigned enc_f(float x) {
    unsigned b = __float_as_uint(x);
    return (b & 0x80000000u) ? ~b : (b | 0x80000000u);   // order-preserving map
}
__device__ __forceinline__ float dec_f(unsigned u) {
    return (u & 0x80000000u) ? __uint_as_float(u ^ 0x80000000u) : __uint_as_float(~u);
}
__device__ __forceinline__ void fma4(float4& a, float s, const float4& w) {
    a.x += s * w.x; a.y += s * w.y; a.z += s * w.z; a.w += s * w.w;
}
__device__ __forceinline__ float dot4(const float4& a, const float4& b) {
    return a.x * b.x + a.y * b.y + a.z * b.z + a.w * b.w;
}

// ---------------- init m (encoded -inf == 0) and s (0) ----------------
__global__ void init_ms(unsigned* __restrict__ m_enc, float* __restrict__ s, int n4) {
    int i = blockIdx.x * blockDim.x + threadIdx.x;
    if (i < n4) { m_enc[i] = 0u; s[i] = 0.0f; }
}

// ---------------- fused GEMM + logits + residual init ----------------
// block 256: c = tid&15 -> cols {4c..4c+3} and {64+4c..64+4c+3}; g = tid>>4 -> rows g+16*rr
__global__ __launch_bounds__(256, 1) void gemm_gat(
    const float* __restrict__ feat, const float* __restrict__ fc_w,
    const float* __restrict__ attn_src, const float* __restrict__ attn_dst,
    float* __restrict__ h, float* __restrict__ e_src, float* __restrict__ e_dst,
    float* __restrict__ out, int N)
{
    __shared__ float wT[HD * WT_PITCH];       // wT[k][o] = fc_w[o][k]
    __shared__ float fs[GROWS * FS_PITCH];    // fs[r][k]
    const int tid = threadIdx.x;
    const int row0 = blockIdx.x * GROWS;

    // load + transpose fc_w into LDS (coalesced global read)
    for (int i = tid; i < HD * HD; i += 256) {
        int o = i >> 7, k = i & 127;
        wT[k * WT_PITCH + o] = fc_w[i];
    }
    // load feat tile; also write residual into out
    float4* fs4w = (float4*)fs;
    for (int i = tid; i < GROWS * 32; i += 256) {
        int r = i >> 5, j = i & 31;
        int rowg = row0 + r;
        float4 v = make_float4(0.f, 0.f, 0.f, 0.f);
        if (rowg < N) v = ((const float4*)feat)[(size_t)rowg * 32 + j];
        fs4w[r * (FS_PITCH / 4) + j] = v;
        if (rowg < N) ((float4*)out)[(size_t)rowg * 32 + j] = v;
    }
    __syncthreads();

    const int c = tid & 15;
    const int g = tid >> 4;
    float4 acc0[8], acc1[8];
#pragma unroll
    for (int rr = 0; rr < 8; rr++) {
        acc0[rr] = make_float4(0.f, 0.f, 0.f, 0.f);
        acc1[rr] = make_float4(0.f, 0.f, 0.f, 0.f);
    }
    const float4* wT4 = (const float4*)wT;
    const float4* fs4 = (const float4*)fs;
#pragma unroll 4
    for (int k4 = 0; k4 < 32; k4++) {
        float4 w0a = wT4[(k4 * 4 + 0) * (WT_PITCH / 4) + c];
        float4 w0b = wT4[(k4 * 4 + 1) * (WT_PITCH / 4) + c];
        float4 w0c = wT4[(k4 * 4 + 2) * (WT_PITCH / 4) + c];
        float4 w0d = wT4[(k4 * 4 + 3) * (WT_PITCH / 4) + c];
        float4 w1a = wT4[(k4 * 4 + 0) * (WT_PITCH / 4) + 16 + c];
        float4 w1b = wT4[(k4 * 4 + 1) * (WT_PITCH / 4) + 16 + c];
        float4 w1c = wT4[(k4 * 4 + 2) * (WT_PITCH / 4) + 16 + c];
        float4 w1d = wT4[(k4 * 4 + 3) * (WT_PITCH / 4) + 16 + c];
#pragma unroll
        for (int rr = 0; rr < 8; rr++) {
            float4 f = fs4[(g + rr * 16) * (FS_PITCH / 4) + k4];
            fma4(acc0[rr], f.x, w0a); fma4(acc0[rr], f.y, w0b);
            fma4(acc0[rr], f.z, w0c); fma4(acc0[rr], f.w, w0d);
            fma4(acc1[rr], f.x, w1a); fma4(acc1[rr], f.y, w1b);
            fma4(acc1[rr], f.z, w1c); fma4(acc1[rr], f.w, w1d);
        }
    }

    // attn vectors for my columns
    float4 as0 = ((const float4*)attn_src)[c];
    float4 as1 = ((const float4*)attn_src)[16 + c];
    float4 ad0 = ((const float4*)attn_dst)[c];
    float4 ad1 = ((const float4*)attn_dst)[16 + c];
    const int head0 = c >> 3;        // cols 4c..4c+3  -> head 0 or 1
    const int head1 = 2 + (c >> 3);  // cols 64+4c..   -> head 2 or 3

#pragma unroll
    for (int rr = 0; rr < 8; rr++) {
        int rowg = row0 + g + rr * 16;
        bool ok = rowg < N;
        if (ok) {
            ((float4*)h)[(size_t)rowg * 32 + c] = acc0[rr];
            ((float4*)h)[(size_t)rowg * 32 + 16 + c] = acc1[rr];
        }
        float es0 = dot4(acc0[rr], as0), es1 = dot4(acc1[rr], as1);
        float ed0 = dot4(acc0[rr], ad0), ed1 = dot4(acc1[rr], ad1);
        // reduce over the 8 lanes sharing (g, head): c in [8h..8h+7], contiguous lanes
        es0 += __shfl_xor(es0, 1); es0 += __shfl_xor(es0, 2); es0 += __shfl_xor(es0, 4);
        es1 += __shfl_xor(es1, 1); es1 += __shfl_xor(es1, 2); es1 += __shfl_xor(es1, 4);
        ed0 += __shfl_xor(ed0, 1); ed0 += __shfl_xor(ed0, 2); ed0 += __shfl_xor(ed0, 4);
        ed1 += __shfl_xor(ed1, 1); ed1 += __shfl_xor(ed1, 2); ed1 += __shfl_xor(ed1, 4);
        if (ok && (c & 7) == 0) {
            e_src[rowg * 4 + head0] = es0;
            e_src[rowg * 4 + head1] = es1;
            e_dst[rowg * 4 + head0] = ed0;
            e_dst[rowg * 4 + head1] = ed1;
        }
    }
}

// ---------------- edge pass 1: segment max (encoded float atomicMax) ----------------
__global__ void edge_max(const int* __restrict__ src, const int* __restrict__ dst,
                         const float* __restrict__ e_src, const float* __restrict__ e_dst,
                         unsigned* __restrict__ m_enc, int E)
{
    int e = blockIdx.x * blockDim.x + threadIdx.x;
    if (e >= E) return;
    int si = src[e], di = dst[e];
    float4 es = ((const float4*)e_src)[si];
    float4 ed = ((const float4*)e_dst)[di];
    float v0 = es.x + ed.x; v0 = v0 > 0.f ? v0 : 0.2f * v0;
    float v1 = es.y + ed.y; v1 = v1 > 0.f ? v1 : 0.2f * v1;
    float v2 = es.z + ed.z; v2 = v2 > 0.f ? v2 : 0.2f * v2;
    float v3 = es.w + ed.w; v3 = v3 > 0.f ? v3 : 0.2f * v3;
    atomicMax(&m_enc[di * 4 + 0], enc_f(v0));
    atomicMax(&m_enc[di * 4 + 1], enc_f(v1));
    atomicMax(&m_enc[di * 4 + 2], enc_f(v2));
    atomicMax(&m_enc[di * 4 + 3], enc_f(v3));
}

// ---------------- edge pass 2: exp-sum ----------------
__global__ void edge_sum(const int* __restrict__ src, const int* __restrict__ dst,
                         const float* __restrict__ e_src, const float* __restrict__ e_dst,
                         const unsigned* __restrict__ m_enc, float* __restrict__ s, int E)
{
    int e = blockIdx.x * blockDim.x + threadIdx.x;
    if (e >= E) return;
    int si = src[e], di = dst[e];
    float4 es = ((const float4*)e_src)[si];
    float4 ed = ((const float4*)e_dst)[di];
    float v0 = es.x + ed.x; v0 = v0 > 0.f ? v0 : 0.2f * v0;
    float v1 = es.y + ed.y; v1 = v1 > 0.f ? v1 : 0.2f * v1;
    float v2 = es.z + ed.z; v2 = v2 > 0.f ? v2 : 0.2f * v2;
    float v3 = es.w + ed.w; v3 = v3 > 0.f ? v3 : 0.2f * v3;
    atomicAdd(&s[di * 4 + 0], __expf(v0 - dec_f(m_enc[di * 4 + 0])));
    atomicAdd(&s[di * 4 + 1], __expf(v1 - dec_f(m_enc[di * 4 + 1])));
    atomicAdd(&s[di * 4 + 2], __expf(v2 - dec_f(m_enc[di * 4 + 2])));
    atomicAdd(&s[di * 4 + 3], __expf(v3 - dec_f(m_enc[di * 4 + 3])));
}

// ---------------- edge pass 3: weighted scatter-sum ----------------
// wave handles 4 edges; 16 lanes/edge, each lane does 8 contiguous floats (one head)
__global__ __launch_bounds__(256) void edge_agg(
    const int* __restrict__ src, const int* __restrict__ dst,
    const float* __restrict__ e_src, const float* __restrict__ e_dst,
    const unsigned* __restrict__ m_enc, const float* __restrict__ s,
    const float* __restrict__ h, float* __restrict__ out, int E)
{
    int gtid = blockIdx.x * blockDim.x + threadIdx.x;
    int wave = gtid >> 6;
    int lane = threadIdx.x & 63;
    int e = wave * 4 + (lane >> 4);
    if (e >= E) return;
    int l = lane & 15;
    int si = src[e], di = dst[e];
    int head = l >> 2;                      // elements l*8..l*8+7 -> head = l/4
    float esv = e_src[si * 4 + head];
    float edv = e_dst[di * 4 + head];
    float v = esv + edv; v = v > 0.f ? v : 0.2f * v;
    float sden = s[di * 4 + head];
    float w = __expf(v - dec_f(m_enc[di * 4 + head])) / sden;

    const float4* hrow = (const float4*)(h + (size_t)si * 128);
    float4 a = hrow[l * 2], b = hrow[l * 2 + 1];
    float* o = out + (size_t)di * 128 + l * 8;
    atomicAdd(o + 0, a.x * w); atomicAdd(o + 1, a.y * w);
    atomicAdd(o + 2, a.z * w); atomicAdd(o + 3, a.w * w);
    atomicAdd(o + 4, b.x * w); atomicAdd(o + 5, b.y * w);
    atomicAdd(o + 6, b.z * w); atomicAdd(o + 7, b.w * w);
}

extern "C" void kernel_launch(void* const* d_in, const int* in_sizes, int n_in,
                              void* d_out, int out_size, void* d_ws, size_t ws_size,
                              hipStream_t stream) {
    const float* feat     = (const float*)d_in[0];
    const float* fc_w     = (const float*)d_in[1];
    const float* attn_src = (const float*)d_in[2];
    const float* attn_dst = (const float*)d_in[3];
    const int*   src      = (const int*)d_in[4];
    const int*   dst      = (const int*)d_in[5];
    const int N = in_sizes[0] / HD;
    const int E = in_sizes[4];
    float* out = (float*)d_out;

    // workspace layout (all fp32/u32): h[N*128] | e_src[N*4] | e_dst[N*4] | m_enc[N*4] | s[N*4]
    float* h      = (float*)d_ws;
    float* e_src  = h + (size_t)N * HD;
    float* e_dst  = e_src + (size_t)N * NHEADS;
    unsigned* m_enc = (unsigned*)(e_dst + (size_t)N * NHEADS);
    float* s      = (float*)(m_enc + (size_t)N * NHEADS);

    init_ms<<<(N * NHEADS + 255) / 256, 256, 0, stream>>>(m_enc, s, N * NHEADS);
    gemm_gat<<<(N + GROWS - 1) / GROWS, 256, 0, stream>>>(
        feat, fc_w, attn_src, attn_dst, h, e_src, e_dst, out, N);
    edge_max<<<(E + 255) / 256, 256, 0, stream>>>(src, dst, e_src, e_dst, m_enc, E);
    edge_sum<<<(E + 255) / 256, 256, 0, stream>>>(src, dst, e_src, e_dst, m_enc, s, E);
    edge_agg<<<(E + 15) / 16, 256, 0, stream>>>(src, dst, e_src, e_dst, m_enc, s, h, out, E);
}

// Round 3
// 682.762 us; speedup vs baseline: 9.3281x; 9.3281x over previous
//
#include <hip/hip_runtime.h>

#define HD 128        // NUM_HEADS*OUT_DIM == IN_DIM
#define NHEADS 4
#define GROWS 128     // rows per gemm block
#define WT_PITCH 132  // padded LDS pitch for transposed weights
#define FS_PITCH 132  // padded LDS pitch for feat tile

__device__ __forceinline__ void fma4(float4& a, float s, const float4& w) {
    a.x += s * w.x; a.y += s * w.y; a.z += s * w.z; a.w += s * w.w;
}
__device__ __forceinline__ float dot4(const float4& a, const float4& b) {
    return a.x * b.x + a.y * b.y + a.z * b.z + a.w * b.w;
}

// ---------------- zero the histogram ----------------
__global__ void zero_counts(int* __restrict__ counts, int N) {
    int i = blockIdx.x * blockDim.x + threadIdx.x;
    if (i < N) counts[i] = 0;
}

// ---------------- histogram of dst ----------------
__global__ void hist_dst(const int* __restrict__ dst, int* __restrict__ counts, int E) {
    int e = blockIdx.x * blockDim.x + threadIdx.x;
    if (e < E) atomicAdd(&counts[dst[e]], 1);
}

// ---------------- single-block chunked exclusive scan: counts -> offsets, cursor ----------------
__global__ __launch_bounds__(1024) void scan_offsets(const int* __restrict__ counts,
        int* __restrict__ offsets, int* __restrict__ cursor, int N) {
    __shared__ int wsum[16];
    __shared__ int s_carry;
    const int tid = threadIdx.x;
    const int lane = tid & 63, wid = tid >> 6;
    if (tid == 0) s_carry = 0;
    __syncthreads();
    for (int base = 0; base < N; base += 4096) {
        int i0 = base + tid * 4;
        int v[4];
#pragma unroll
        for (int j = 0; j < 4; j++) v[j] = (i0 + j < N) ? counts[i0 + j] : 0;
        int local = v[0] + v[1] + v[2] + v[3];
        int incl = local;
#pragma unroll
        for (int off = 1; off < 64; off <<= 1) {
            int t = __shfl_up(incl, off);
            if (lane >= off) incl += t;
        }
        if (lane == 63) wsum[wid] = incl;
        __syncthreads();
        int woff = 0;
        for (int w = 0; w < wid; w++) woff += wsum[w];
        int excl = s_carry + woff + incl - local;
#pragma unroll
        for (int j = 0; j < 4; j++) {
            if (i0 + j < N) { offsets[i0 + j] = excl; cursor[i0 + j] = excl; }
            excl += v[j];
        }
        __syncthreads();
        if (tid == 1023) s_carry += woff + incl;   // total of this chunk
        __syncthreads();
    }
    if (tid == 0) offsets[N] = s_carry;
}

// ---------------- scatter edges into dst-sorted order ----------------
__global__ void scatter_edges(const int* __restrict__ src, const int* __restrict__ dst,
                              int* __restrict__ cursor, int* __restrict__ src_sorted, int E) {
    int e = blockIdx.x * blockDim.x + threadIdx.x;
    if (e >= E) return;
    int pos = atomicAdd(&cursor[dst[e]], 1);
    src_sorted[pos] = src[e];
}

// ---------------- fused GEMM + logits + residual init ----------------
// block 256: c = tid&15 -> cols {4c..4c+3} and {64+4c..64+4c+3}; g = tid>>4 -> rows g+16*rr
__global__ __launch_bounds__(256, 1) void gemm_gat(
    const float* __restrict__ feat, const float* __restrict__ fc_w,
    const float* __restrict__ attn_src, const float* __restrict__ attn_dst,
    float* __restrict__ h, float* __restrict__ e_src, float* __restrict__ e_dst,
    float* __restrict__ out, int N)
{
    __shared__ float wT[HD * WT_PITCH];       // wT[k][o] = fc_w[o][k]
    __shared__ float fs[GROWS * FS_PITCH];    // fs[r][k]
    const int tid = threadIdx.x;
    const int row0 = blockIdx.x * GROWS;

    for (int i = tid; i < HD * HD; i += 256) {
        int o = i >> 7, k = i & 127;
        wT[k * WT_PITCH + o] = fc_w[i];
    }
    float4* fs4w = (float4*)fs;
    for (int i = tid; i < GROWS * 32; i += 256) {
        int r = i >> 5, j = i & 31;
        int rowg = row0 + r;
        float4 v = make_float4(0.f, 0.f, 0.f, 0.f);
        if (rowg < N) v = ((const float4*)feat)[(size_t)rowg * 32 + j];
        fs4w[r * (FS_PITCH / 4) + j] = v;
        if (rowg < N) ((float4*)out)[(size_t)rowg * 32 + j] = v;   // residual init
    }
    __syncthreads();

    const int c = tid & 15;
    const int g = tid >> 4;
    float4 acc0[8], acc1[8];
#pragma unroll
    for (int rr = 0; rr < 8; rr++) {
        acc0[rr] = make_float4(0.f, 0.f, 0.f, 0.f);
        acc1[rr] = make_float4(0.f, 0.f, 0.f, 0.f);
    }
    const float4* wT4 = (const float4*)wT;
    const float4* fs4 = (const float4*)fs;
#pragma unroll 4
    for (int k4 = 0; k4 < 32; k4++) {
        float4 w0a = wT4[(k4 * 4 + 0) * (WT_PITCH / 4) + c];
        float4 w0b = wT4[(k4 * 4 + 1) * (WT_PITCH / 4) + c];
        float4 w0c = wT4[(k4 * 4 + 2) * (WT_PITCH / 4) + c];
        float4 w0d = wT4[(k4 * 4 + 3) * (WT_PITCH / 4) + c];
        float4 w1a = wT4[(k4 * 4 + 0) * (WT_PITCH / 4) + 16 + c];
        float4 w1b = wT4[(k4 * 4 + 1) * (WT_PITCH / 4) + 16 + c];
        float4 w1c = wT4[(k4 * 4 + 2) * (WT_PITCH / 4) + 16 + c];
        float4 w1d = wT4[(k4 * 4 + 3) * (WT_PITCH / 4) + 16 + c];
#pragma unroll
        for (int rr = 0; rr < 8; rr++) {
            float4 f = fs4[(g + rr * 16) * (FS_PITCH / 4) + k4];
            fma4(acc0[rr], f.x, w0a); fma4(acc0[rr], f.y, w0b);
            fma4(acc0[rr], f.z, w0c); fma4(acc0[rr], f.w, w0d);
            fma4(acc1[rr], f.x, w1a); fma4(acc1[rr], f.y, w1b);
            fma4(acc1[rr], f.z, w1c); fma4(acc1[rr], f.w, w1d);
        }
    }

    float4 as0 = ((const float4*)attn_src)[c];
    float4 as1 = ((const float4*)attn_src)[16 + c];
    float4 ad0 = ((const float4*)attn_dst)[c];
    float4 ad1 = ((const float4*)attn_dst)[16 + c];
    const int head0 = c >> 3;
    const int head1 = 2 + (c >> 3);

#pragma unroll
    for (int rr = 0; rr < 8; rr++) {
        int rowg = row0 + g + rr * 16;
        bool ok = rowg < N;
        if (ok) {
            ((float4*)h)[(size_t)rowg * 32 + c] = acc0[rr];
            ((float4*)h)[(size_t)rowg * 32 + 16 + c] = acc1[rr];
        }
        float es0 = dot4(acc0[rr], as0), es1 = dot4(acc1[rr], as1);
        float ed0 = dot4(acc0[rr], ad0), ed1 = dot4(acc1[rr], ad1);
        es0 += __shfl_xor(es0, 1); es0 += __shfl_xor(es0, 2); es0 += __shfl_xor(es0, 4);
        es1 += __shfl_xor(es1, 1); es1 += __shfl_xor(es1, 2); es1 += __shfl_xor(es1, 4);
        ed0 += __shfl_xor(ed0, 1); ed0 += __shfl_xor(ed0, 2); ed0 += __shfl_xor(ed0, 4);
        ed1 += __shfl_xor(ed1, 1); ed1 += __shfl_xor(ed1, 2); ed1 += __shfl_xor(ed1, 4);
        if (ok && (c & 7) == 0) {
            e_src[rowg * 4 + head0] = es0;
            e_src[rowg * 4 + head1] = es1;
            e_dst[rowg * 4 + head0] = ed0;
            e_dst[rowg * 4 + head1] = ed1;
        }
    }
}

// ---------------- per-node fused softmax + aggregation: one wave per dst node ----------------
// Phase 1 (lane = grp*4+head, 16 edge-groups x 4 heads): segment max + exp-sum via shfl_xor.
// Phase 2 (lane covers dims 2l..2l+1, head = l>>4): weighted accumulate, single non-atomic write.
__global__ __launch_bounds__(256) void node_agg(
    const int* __restrict__ src_sorted, const int* __restrict__ offsets,
    const float* __restrict__ e_src, const float* __restrict__ e_dst,
    const float* __restrict__ h, float* __restrict__ out, int N)
{
    int n = (blockIdx.x * 256 + threadIdx.x) >> 6;
    int lane = threadIdx.x & 63;
    if (n >= N) return;
    int start = offsets[n], end = offsets[n + 1];
    if (start == end) return;                       // no incoming edges: residual only

    const int head1 = lane & 3;
    const int grp = lane >> 2;
    const float edv = e_dst[n * 4 + head1];

    // phase 1a: segment max
    float m_l = -3.0e38f;
    for (int i = start + grp; i < end; i += 16) {
        int si = src_sorted[i];
        float v = e_src[si * 4 + head1] + edv;
        v = v > 0.f ? v : 0.2f * v;
        m_l = fmaxf(m_l, v);
    }
    m_l = fmaxf(m_l, __shfl_xor(m_l, 4));
    m_l = fmaxf(m_l, __shfl_xor(m_l, 8));
    m_l = fmaxf(m_l, __shfl_xor(m_l, 16));
    m_l = fmaxf(m_l, __shfl_xor(m_l, 32));
    // phase 1b: exp-sum
    float s_l = 0.f;
    for (int i = start + grp; i < end; i += 16) {
        int si = src_sorted[i];
        float v = e_src[si * 4 + head1] + edv;
        v = v > 0.f ? v : 0.2f * v;
        s_l += __expf(v - m_l);
    }
    s_l += __shfl_xor(s_l, 4);
    s_l += __shfl_xor(s_l, 8);
    s_l += __shfl_xor(s_l, 16);
    s_l += __shfl_xor(s_l, 32);

    // phase 2: weighted accumulate (all 64 lanes per edge; 512B coalesced h-row reads)
    const int head2 = lane >> 4;
    const float mh = __shfl(m_l, head2);            // lane `head2` holds head2's stats
    const float inv_s = 1.0f / __shfl(s_l, head2);
    const float edv2 = e_dst[n * 4 + head2];
    float2 acc = make_float2(0.f, 0.f);
    int i = start;
    int si = src_sorted[i];
    for (; i < end; ) {
        int si_next = (i + 1 < end) ? src_sorted[i + 1] : 0;   // prefetch next src idx
        float v = e_src[si * 4 + head2] + edv2;
        v = v > 0.f ? v : 0.2f * v;
        float w = __expf(v - mh) * inv_s;
        float2 hv = ((const float2*)h)[(size_t)si * 64 + lane];
        acc.x += hv.x * w; acc.y += hv.y * w;
        si = si_next; ++i;
    }
    float2* o = (float2*)(out + (size_t)n * HD);
    float2 cur = o[lane];
    cur.x += acc.x; cur.y += acc.y;
    o[lane] = cur;
}

extern "C" void kernel_launch(void* const* d_in, const int* in_sizes, int n_in,
                              void* d_out, int out_size, void* d_ws, size_t ws_size,
                              hipStream_t stream) {
    const float* feat     = (const float*)d_in[0];
    const float* fc_w     = (const float*)d_in[1];
    const float* attn_src = (const float*)d_in[2];
    const float* attn_dst = (const float*)d_in[3];
    const int*   src      = (const int*)d_in[4];
    const int*   dst      = (const int*)d_in[5];
    const int N = in_sizes[0] / HD;
    const int E = in_sizes[4];
    float* out = (float*)d_out;

    // ws layout: h[N*128] | e_src[N*4] | e_dst[N*4] | counts[N] | offsets[N+1] | cursor[N] | src_sorted[E]
    float* h      = (float*)d_ws;
    float* e_src  = h + (size_t)N * HD;
    float* e_dst  = e_src + (size_t)N * NHEADS;
    int* counts     = (int*)(e_dst + (size_t)N * NHEADS);
    int* offsets    = counts + N;
    int* cursor     = offsets + (N + 1);
    int* src_sorted = cursor + N;

    zero_counts<<<(N + 255) / 256, 256, 0, stream>>>(counts, N);
    hist_dst<<<(E + 255) / 256, 256, 0, stream>>>(dst, counts, E);
    scan_offsets<<<1, 1024, 0, stream>>>(counts, offsets, cursor, N);
    scatter_edges<<<(E + 255) / 256, 256, 0, stream>>>(src, dst, cursor, src_sorted, E);
    gemm_gat<<<(N + GROWS - 1) / GROWS, 256, 0, stream>>>(
        feat, fc_w, attn_src, attn_dst, h, e_src, e_dst, out, N);
    node_agg<<<(N + 3) / 4, 256, 0, stream>>>(src_sorted, offsets, e_src, e_dst, h, out, N);
}

// Round 4
// 599.140 us; speedup vs baseline: 10.6300x; 1.1396x over previous
//
#include <hip/hip_runtime.h>

#define HD 128        // NUM_HEADS*OUT_DIM == IN_DIM
#define NHEADS 4
#define MBLK 128      // gemm rows per block
#define APITCH 136    // LDS pitch in ushorts (272B = 68 dwords -> bank spread)

typedef __attribute__((ext_vector_type(8))) short bf16x8;
typedef __attribute__((ext_vector_type(4))) float f32x4;

__device__ __forceinline__ unsigned short f2bf(float x) {   // RNE
    union { float f; unsigned u; } a; a.f = x;
    unsigned r = a.u + 0x7fffu + ((a.u >> 16) & 1u);
    return (unsigned short)(r >> 16);
}

// ---------------- sort pipeline ----------------
__global__ void zero_counts(int* __restrict__ counts, int N) {
    int i = blockIdx.x * blockDim.x + threadIdx.x;
    if (i < N) counts[i] = 0;
}
__global__ void hist_dst(const int* __restrict__ dst, int* __restrict__ counts, int E) {
    int e = blockIdx.x * blockDim.x + threadIdx.x;
    if (e < E) atomicAdd(&counts[dst[e]], 1);
}
__global__ __launch_bounds__(1024) void scan_offsets(const int* __restrict__ counts,
        int* __restrict__ offsets, int* __restrict__ cursor, int N) {
    __shared__ int wsum[16];
    __shared__ int s_carry;
    const int tid = threadIdx.x;
    const int lane = tid & 63, wid = tid >> 6;
    if (tid == 0) s_carry = 0;
    __syncthreads();
    for (int base = 0; base < N; base += 4096) {
        int i0 = base + tid * 4;
        int v[4];
#pragma unroll
        for (int j = 0; j < 4; j++) v[j] = (i0 + j < N) ? counts[i0 + j] : 0;
        int local = v[0] + v[1] + v[2] + v[3];
        int incl = local;
#pragma unroll
        for (int off = 1; off < 64; off <<= 1) {
            int t = __shfl_up(incl, off);
            if (lane >= off) incl += t;
        }
        if (lane == 63) wsum[wid] = incl;
        __syncthreads();
        int woff = 0;
        for (int w = 0; w < wid; w++) woff += wsum[w];
        int excl = s_carry + woff + incl - local;
#pragma unroll
        for (int j = 0; j < 4; j++) {
            if (i0 + j < N) { offsets[i0 + j] = excl; cursor[i0 + j] = excl; }
            excl += v[j];
        }
        __syncthreads();
        if (tid == 1023) s_carry += woff + incl;
        __syncthreads();
    }
    if (tid == 0) offsets[N] = s_carry;
}
__global__ void scatter_edges(const int* __restrict__ src, const int* __restrict__ dst,
                              int* __restrict__ cursor, int* __restrict__ src_sorted, int E) {
    int e = blockIdx.x * blockDim.x + threadIdx.x;
    if (e >= E) return;
    int pos = atomicAdd(&cursor[dst[e]], 1);
    src_sorted[pos] = src[e];
}

// ---------------- exact fp32 logit path: ws[k][o] = sum_d fc_w[h*32+d][k]*attn[h][d] ----------------
__global__ void make_ws(const float* __restrict__ fc_w, const float* __restrict__ attn_src,
                        const float* __restrict__ attn_dst, float* __restrict__ ws) {
    int idx = blockIdx.x * blockDim.x + threadIdx.x;
    if (idx >= 1024) return;
    int k = idx >> 3, o = idx & 7;
    int hh = o & 3;
    const float* av = (o < 4) ? attn_src : attn_dst;
    float s = 0.f;
#pragma unroll 8
    for (int d = 0; d < 32; d++)
        s += fc_w[(hh * 32 + d) * 128 + k] * av[hh * 32 + d];
    ws[k * 8 + o] = s;
}

// one wave per node: e_src/e_dst[n][h] = feat[n,:] . ws[:,o]
__global__ __launch_bounds__(256) void logits(
    const float* __restrict__ feat, const float* __restrict__ ws,
    float* __restrict__ e_src, float* __restrict__ e_dst, int N)
{
    int n = (blockIdx.x * 256 + threadIdx.x) >> 6;
    int lane = threadIdx.x & 63;
    if (n >= N) return;
    float2 f = ((const float2*)feat)[(size_t)n * 64 + lane];
    const float4* w4 = (const float4*)(ws + lane * 16);
    float4 wa = w4[0], wb = w4[1], wc = w4[2], wd = w4[3];
    float p[8];
    p[0] = f.x * wa.x + f.y * wc.x;  p[1] = f.x * wa.y + f.y * wc.y;
    p[2] = f.x * wa.z + f.y * wc.z;  p[3] = f.x * wa.w + f.y * wc.w;
    p[4] = f.x * wb.x + f.y * wd.x;  p[5] = f.x * wb.y + f.y * wd.y;
    p[6] = f.x * wb.z + f.y * wd.z;  p[7] = f.x * wb.w + f.y * wd.w;
#pragma unroll
    for (int o = 0; o < 8; o++) {
#pragma unroll
        for (int off = 1; off < 64; off <<= 1) p[o] += __shfl_xor(p[o], off);
    }
    if (lane < 4)      e_src[n * 4 + lane] = p[lane];
    else if (lane < 8) e_dst[n * 4 + lane - 4] = p[lane];
}

// ---------------- bf16 MFMA GEMM: h = feat @ fc_w.T (bf16 out), fused residual init ----------------
// block 256 = 4 waves; wave w: rows w*32..w*32+31 (2 row-tiles), all 128 cols (8 col-tiles); K=128 in 4 steps
__global__ __launch_bounds__(256, 2) void gemm_mfma(
    const float* __restrict__ feat, const float* __restrict__ fc_w,
    unsigned short* __restrict__ h, float* __restrict__ out, int N)
{
    __shared__ unsigned short As[MBLK * APITCH];   // feat tile [r][k] bf16
    __shared__ unsigned short Bs[HD * APITCH];     // fc_w      [o][k] bf16
    const int tid = threadIdx.x;
    const int row0 = blockIdx.x * MBLK;

    // stage B (fc_w is already [n][k] = B^T row-major -> lanes get contiguous k)
    for (int i = tid; i < 128 * 32; i += 256) {
        int o = i >> 5, j = i & 31;
        float4 v = ((const float4*)fc_w)[i];
        ushort4 u; u.x = f2bf(v.x); u.y = f2bf(v.y); u.z = f2bf(v.z); u.w = f2bf(v.w);
        *(ushort4*)&Bs[o * APITCH + j * 4] = u;
    }
    // stage A + residual init
    for (int i = tid; i < MBLK * 32; i += 256) {
        int r = i >> 5, j = i & 31;
        int rowg = row0 + r;
        float4 v = make_float4(0.f, 0.f, 0.f, 0.f);
        if (rowg < N) {
            v = ((const float4*)feat)[(size_t)rowg * 32 + j];
            ((float4*)out)[(size_t)rowg * 32 + j] = v;
        }
        ushort4 u; u.x = f2bf(v.x); u.y = f2bf(v.y); u.z = f2bf(v.z); u.w = f2bf(v.w);
        *(ushort4*)&As[r * APITCH + j * 4] = u;
    }
    __syncthreads();

    const int w = tid >> 6, lane = tid & 63, quad = lane >> 4, lr = lane & 15;
    f32x4 acc[2][8];
#pragma unroll
    for (int rt = 0; rt < 2; rt++)
#pragma unroll
        for (int ct = 0; ct < 8; ct++) acc[rt][ct] = (f32x4){0.f, 0.f, 0.f, 0.f};

#pragma unroll
    for (int ks = 0; ks < 4; ks++) {
        const int k0 = ks * 32 + quad * 8;
        bf16x8 a0 = *(const bf16x8*)&As[(w * 32 + lr) * APITCH + k0];
        bf16x8 a1 = *(const bf16x8*)&As[(w * 32 + 16 + lr) * APITCH + k0];
        bf16x8 bf[8];
#pragma unroll
        for (int ct = 0; ct < 8; ct++)
            bf[ct] = *(const bf16x8*)&Bs[(ct * 16 + lr) * APITCH + k0];
#pragma unroll
        for (int ct = 0; ct < 8; ct++) {
            acc[0][ct] = __builtin_amdgcn_mfma_f32_16x16x32_bf16(a0, bf[ct], acc[0][ct], 0, 0, 0);
            acc[1][ct] = __builtin_amdgcn_mfma_f32_16x16x32_bf16(a1, bf[ct], acc[1][ct], 0, 0, 0);
        }
    }

    // epilogue: C/D layout col=lane&15, row=quad*4+reg  [verified m89/m91]
#pragma unroll
    for (int rt = 0; rt < 2; rt++) {
#pragma unroll
        for (int ct = 0; ct < 8; ct++) {
            int col = ct * 16 + lr;
#pragma unroll
            for (int reg = 0; reg < 4; reg++) {
                int row = row0 + w * 32 + rt * 16 + quad * 4 + reg;
                if (row < N) h[(size_t)row * 128 + col] = f2bf(acc[rt][ct][reg]);
            }
        }
    }
}

// ---------------- per-node fused softmax + aggregation (bf16 h, chunked weights) ----------------
__global__ __launch_bounds__(256) void node_agg(
    const int* __restrict__ src_sorted, const int* __restrict__ offsets,
    const float* __restrict__ e_src, const float* __restrict__ e_dst,
    const unsigned short* __restrict__ h, float* __restrict__ out, int N)
{
    int n = (blockIdx.x * 256 + threadIdx.x) >> 6;
    int lane = threadIdx.x & 63;
    if (n >= N) return;
    int start = offsets[n], end = offsets[n + 1];
    if (start == end) return;                     // residual only

    const int hh = lane & 3;
    const int grp = lane >> 2;
    const float edv = e_dst[n * 4 + hh];

    // segment max
    float m_l = -3.0e38f;
    for (int i = start + grp; i < end; i += 16) {
        int si = src_sorted[i];
        float v = e_src[si * 4 + hh] + edv;
        v = v > 0.f ? v : 0.2f * v;
        m_l = fmaxf(m_l, v);
    }
    m_l = fmaxf(m_l, __shfl_xor(m_l, 4));
    m_l = fmaxf(m_l, __shfl_xor(m_l, 8));
    m_l = fmaxf(m_l, __shfl_xor(m_l, 16));
    m_l = fmaxf(m_l, __shfl_xor(m_l, 32));
    // exp-sum
    float s_l = 0.f;
    for (int i = start + grp; i < end; i += 16) {
        int si = src_sorted[i];
        float v = e_src[si * 4 + hh] + edv;
        v = v > 0.f ? v : 0.2f * v;
        s_l += __expf(v - m_l);
    }
    s_l += __shfl_xor(s_l, 4);
    s_l += __shfl_xor(s_l, 8);
    s_l += __shfl_xor(s_l, 16);
    s_l += __shfl_xor(s_l, 32);
    const float inv_s = 1.0f / s_l;

    // weighted accumulate: 16-edge chunks; lanes grp*4+hh compute weights once, broadcast
    const int head2 = lane >> 4;                  // lane covers cols 2*lane, 2*lane+1
    float2 acc = make_float2(0.f, 0.f);
    for (int chunk = start; chunk < end; chunk += 16) {
        int nc = end - chunk; if (nc > 16) nc = 16;
        float wv = 0.f; int si_l = 0;
        if (grp < nc) {
            si_l = src_sorted[chunk + grp];
            float v = e_src[si_l * 4 + hh] + edv;
            v = v > 0.f ? v : 0.2f * v;
            wv = __expf(v - m_l) * inv_s;
        }
        for (int j = 0; j < nc; j++) {
            int si = __shfl(si_l, j * 4);
            float ww = __shfl(wv, j * 4 + head2);
            unsigned hv = *(const unsigned*)&h[(size_t)si * 128 + lane * 2];
            float fx = __uint_as_float(hv << 16);
            float fy = __uint_as_float(hv & 0xffff0000u);
            acc.x += fx * ww; acc.y += fy * ww;
        }
    }
    float2* o = (float2*)(out + (size_t)n * HD);
    float2 cur = o[lane];
    cur.x += acc.x; cur.y += acc.y;
    o[lane] = cur;
}

extern "C" void kernel_launch(void* const* d_in, const int* in_sizes, int n_in,
                              void* d_out, int out_size, void* d_ws, size_t ws_size,
                              hipStream_t stream) {
    const float* feat     = (const float*)d_in[0];
    const float* fc_w     = (const float*)d_in[1];
    const float* attn_src = (const float*)d_in[2];
    const float* attn_dst = (const float*)d_in[3];
    const int*   src      = (const int*)d_in[4];
    const int*   dst      = (const int*)d_in[5];
    const int N = in_sizes[0] / HD;
    const int E = in_sizes[4];
    float* out = (float*)d_out;

    // ws: h_bf16[N*128] | e_src[N*4] | e_dst[N*4] | ws_attn[1024] | counts[N] | offsets[N+1] | cursor[N] | src_sorted[E]
    unsigned short* h = (unsigned short*)d_ws;
    float* e_src  = (float*)(h + (size_t)N * HD);
    float* e_dst  = e_src + (size_t)N * NHEADS;
    float* ws_at  = e_dst + (size_t)N * NHEADS;
    int* counts     = (int*)(ws_at + 1024);
    int* offsets    = counts + N;
    int* cursor     = offsets + (N + 1);
    int* src_sorted = cursor + N;

    zero_counts<<<(N + 255) / 256, 256, 0, stream>>>(counts, N);
    hist_dst<<<(E + 255) / 256, 256, 0, stream>>>(dst, counts, E);
    scan_offsets<<<1, 1024, 0, stream>>>(counts, offsets, cursor, N);
    scatter_edges<<<(E + 255) / 256, 256, 0, stream>>>(src, dst, cursor, src_sorted, E);
    make_ws<<<4, 256, 0, stream>>>(fc_w, attn_src, attn_dst, ws_at);
    logits<<<(N + 3) / 4, 256, 0, stream>>>(feat, ws_at, e_src, e_dst, N);
    gemm_mfma<<<(N + MBLK - 1) / MBLK, 256, 0, stream>>>(feat, fc_w, h, out, N);
    node_agg<<<(N + 3) / 4, 256, 0, stream>>>(src_sorted, offsets, e_src, e_dst, h, out, N);
}

// Round 6
// 424.916 us; speedup vs baseline: 14.9885x; 1.4100x over previous
//
#include <hip/hip_runtime.h>

#define HD 128        // NUM_HEADS*OUT_DIM == IN_DIM
#define NHEADS 4
#define MBLK 128      // gemm rows per block
#define APITCH 136    // LDS pitch in ushorts

typedef __attribute__((ext_vector_type(8))) short bf16x8;
typedef __attribute__((ext_vector_type(4))) float f32x4;

__device__ __forceinline__ unsigned short f2bf(float x) {   // RNE
    union { float f; unsigned u; } a; a.f = x;
    unsigned r = a.u + 0x7fffu + ((a.u >> 16) & 1u);
    return (unsigned short)(r >> 16);
}
__device__ __forceinline__ float bf2f(unsigned short u) {
    return __uint_as_float(((unsigned)u) << 16);
}

// ---------------- sort pipeline ----------------
__global__ void zero_counts(int* __restrict__ counts, int N) {
    int i = blockIdx.x * blockDim.x + threadIdx.x;
    if (i < N) counts[i] = 0;
}
__global__ void hist_dst(const int* __restrict__ dst, int* __restrict__ counts, int E) {
    int e = blockIdx.x * blockDim.x + threadIdx.x;
    if (e < E) atomicAdd(&counts[dst[e]], 1);
}
// pass1: per-block (1024 elems) sums
__global__ __launch_bounds__(256) void scan_pass1(const int* __restrict__ counts,
                                                  int* __restrict__ bsum, int N) {
    __shared__ int wsum[4];
    int tid = threadIdx.x;
    int i0 = blockIdx.x * 1024 + tid * 4;
    int s = 0;
#pragma unroll
    for (int j = 0; j < 4; j++) s += (i0 + j < N) ? counts[i0 + j] : 0;
#pragma unroll
    for (int off = 1; off < 64; off <<= 1) s += __shfl_xor(s, off);
    if ((tid & 63) == 0) wsum[tid >> 6] = s;
    __syncthreads();
    if (tid == 0) bsum[blockIdx.x] = wsum[0] + wsum[1] + wsum[2] + wsum[3];
}
// pass2: single block exclusive-scans the (<=1024) block sums in place
__global__ __launch_bounds__(1024) void scan_pass2(int* __restrict__ bsum, int nb) {
    __shared__ int sm[1024];
    int tid = threadIdx.x;
    int orig = (tid < nb) ? bsum[tid] : 0;
    sm[tid] = orig;
    __syncthreads();
    for (int off = 1; off < 1024; off <<= 1) {
        int v = (tid >= off) ? sm[tid - off] : 0;
        __syncthreads();
        sm[tid] += v;
        __syncthreads();
    }
    if (tid < nb) bsum[tid] = sm[tid] - orig;   // exclusive
}
// pass3: local scan + block base -> offsets, cursor
__global__ __launch_bounds__(256) void scan_pass3(const int* __restrict__ counts,
        const int* __restrict__ bsum, int* __restrict__ offsets, int* __restrict__ cursor,
        int N, int E) {
    __shared__ int wsum[4];
    int tid = threadIdx.x, lane = tid & 63, wid = tid >> 6;
    int i0 = blockIdx.x * 1024 + tid * 4;
    int v[4];
#pragma unroll
    for (int j = 0; j < 4; j++) v[j] = (i0 + j < N) ? counts[i0 + j] : 0;
    int local = v[0] + v[1] + v[2] + v[3];
    int incl = local;
#pragma unroll
    for (int off = 1; off < 64; off <<= 1) {
        int t = __shfl_up(incl, off);
        if (lane >= off) incl += t;
    }
    if (lane == 63) wsum[wid] = incl;
    __syncthreads();
    int base = bsum[blockIdx.x];
    for (int w = 0; w < wid; w++) base += wsum[w];
    int excl = base + incl - local;
#pragma unroll
    for (int j = 0; j < 4; j++) {
        if (i0 + j < N) { offsets[i0 + j] = excl; cursor[i0 + j] = excl; }
        excl += v[j];
    }
    if (blockIdx.x == 0 && tid == 0) offsets[N] = E;
}
// scatter: dst-sorted src index + bf16 leaky logits per edge (4 heads)
__global__ void scatter_edges(const int* __restrict__ src, const int* __restrict__ dst,
                              int* __restrict__ cursor, int* __restrict__ src_sorted,
                              const float* __restrict__ e_src, const float* __restrict__ e_dst,
                              unsigned short* __restrict__ esort, int E) {
    int e = blockIdx.x * blockDim.x + threadIdx.x;
    if (e >= E) return;
    int si = src[e], di = dst[e];
    int pos = atomicAdd(&cursor[di], 1);
    src_sorted[pos] = si;
    float4 es = ((const float4*)e_src)[si];
    float4 ed = ((const float4*)e_dst)[di];
    float v0 = es.x + ed.x; v0 = v0 > 0.f ? v0 : 0.2f * v0;
    float v1 = es.y + ed.y; v1 = v1 > 0.f ? v1 : 0.2f * v1;
    float v2 = es.z + ed.z; v2 = v2 > 0.f ? v2 : 0.2f * v2;
    float v3 = es.w + ed.w; v3 = v3 > 0.f ? v3 : 0.2f * v3;
    ushort4 u; u.x = f2bf(v0); u.y = f2bf(v1); u.z = f2bf(v2); u.w = f2bf(v3);
    *(ushort4*)&esort[(size_t)pos * 4] = u;
}

// ---------------- exact fp32 logit path ----------------
__global__ void make_ws(const float* __restrict__ fc_w, const float* __restrict__ attn_src,
                        const float* __restrict__ attn_dst, float* __restrict__ ws) {
    int idx = blockIdx.x * blockDim.x + threadIdx.x;
    if (idx >= 1024) return;
    int k = idx >> 3, o = idx & 7;
    int hh = o & 3;
    const float* av = (o < 4) ? attn_src : attn_dst;
    float s = 0.f;
#pragma unroll 8
    for (int d = 0; d < 32; d++)
        s += fc_w[(hh * 32 + d) * 128 + k] * av[hh * 32 + d];
    ws[k * 8 + o] = s;
}
// 32 lanes per node, 2 nodes per wave; p[0..3]=src logits, p[4..7]=dst logits
__global__ __launch_bounds__(256) void logits(
    const float* __restrict__ feat, const float* __restrict__ ws,
    float* __restrict__ e_src, float* __restrict__ e_dst, int N)
{
    int widx = (blockIdx.x * 256 + threadIdx.x) >> 6;
    int lane = threadIdx.x & 63;
    int sub = lane >> 5, sl = lane & 31;
    int n = widx * 2 + sub;
    if (n >= N) return;
    float4 f = ((const float4*)feat)[(size_t)n * 32 + sl];
    const float* wr = ws + sl * 32;   // rows k = sl*4 .. sl*4+3
    float p[8];
#pragma unroll
    for (int o = 0; o < 8; o++)
        p[o] = f.x * wr[o] + f.y * wr[8 + o] + f.z * wr[16 + o] + f.w * wr[24 + o];
#pragma unroll
    for (int o = 0; o < 8; o++) {
#pragma unroll
        for (int off = 1; off < 32; off <<= 1) p[o] += __shfl_xor(p[o], off);
    }
    if (sl < 4)      e_src[n * 4 + sl] = p[sl];
    else if (sl < 8) e_dst[n * 4 + sl - 4] = p[sl];   // p[4..7] are the dst logits (R5 bug: was p[sl-4])
}

// ---------------- bf16 MFMA GEMM: h = feat @ fc_w.T (bf16 out), fused residual init ----------------
__global__ __launch_bounds__(256, 2) void gemm_mfma(
    const float* __restrict__ feat, const float* __restrict__ fc_w,
    unsigned short* __restrict__ h, float* __restrict__ out, int N)
{
    __shared__ unsigned short As[MBLK * APITCH];
    __shared__ unsigned short Bs[HD * APITCH];
    const int tid = threadIdx.x;
    const int row0 = blockIdx.x * MBLK;

    for (int i = tid; i < 128 * 32; i += 256) {
        int o = i >> 5, j = i & 31;
        float4 v = ((const float4*)fc_w)[i];
        ushort4 u; u.x = f2bf(v.x); u.y = f2bf(v.y); u.z = f2bf(v.z); u.w = f2bf(v.w);
        *(ushort4*)&Bs[o * APITCH + j * 4] = u;
    }
    for (int i = tid; i < MBLK * 32; i += 256) {
        int r = i >> 5, j = i & 31;
        int rowg = row0 + r;
        float4 v = make_float4(0.f, 0.f, 0.f, 0.f);
        if (rowg < N) {
            v = ((const float4*)feat)[(size_t)rowg * 32 + j];
            ((float4*)out)[(size_t)rowg * 32 + j] = v;   // residual init
        }
        ushort4 u; u.x = f2bf(v.x); u.y = f2bf(v.y); u.z = f2bf(v.z); u.w = f2bf(v.w);
        *(ushort4*)&As[r * APITCH + j * 4] = u;
    }
    __syncthreads();

    const int w = tid >> 6, lane = tid & 63, quad = lane >> 4, lr = lane & 15;
    f32x4 acc[2][8];
#pragma unroll
    for (int rt = 0; rt < 2; rt++)
#pragma unroll
        for (int ct = 0; ct < 8; ct++) acc[rt][ct] = (f32x4){0.f, 0.f, 0.f, 0.f};

#pragma unroll
    for (int ks = 0; ks < 4; ks++) {
        const int k0 = ks * 32 + quad * 8;
        bf16x8 a0 = *(const bf16x8*)&As[(w * 32 + lr) * APITCH + k0];
        bf16x8 a1 = *(const bf16x8*)&As[(w * 32 + 16 + lr) * APITCH + k0];
        bf16x8 bf[8];
#pragma unroll
        for (int ct = 0; ct < 8; ct++)
            bf[ct] = *(const bf16x8*)&Bs[(ct * 16 + lr) * APITCH + k0];
#pragma unroll
        for (int ct = 0; ct < 8; ct++) {
            acc[0][ct] = __builtin_amdgcn_mfma_f32_16x16x32_bf16(a0, bf[ct], acc[0][ct], 0, 0, 0);
            acc[1][ct] = __builtin_amdgcn_mfma_f32_16x16x32_bf16(a1, bf[ct], acc[1][ct], 0, 0, 0);
        }
    }
#pragma unroll
    for (int rt = 0; rt < 2; rt++) {
#pragma unroll
        for (int ct = 0; ct < 8; ct++) {
            int col = ct * 16 + lr;
#pragma unroll
            for (int reg = 0; reg < 4; reg++) {
                int row = row0 + w * 32 + rt * 16 + quad * 4 + reg;
                if (row < N) h[(size_t)row * 128 + col] = f2bf(acc[rt][ct][reg]);
            }
        }
    }
}

// ---------------- per-node fused softmax + aggregation ----------------
// phase 1: online max+sum, coalesced esort reads (lane = grp*4+hh).
// phase 2: 4 edges in flight x 16 lanes x 16B h loads; combine via shfl_xor(16,32).
__global__ __launch_bounds__(256) void node_agg(
    const int* __restrict__ src_sorted, const int* __restrict__ offsets,
    const unsigned short* __restrict__ esort,
    const unsigned short* __restrict__ h, float* __restrict__ out, int N)
{
    int n = (blockIdx.x * 256 + threadIdx.x) >> 6;
    int lane = threadIdx.x & 63;
    if (n >= N) return;
    int start = offsets[n], end = offsets[n + 1];
    if (start == end) return;                     // residual only

    const int hh = lane & 3;
    const int grp = lane >> 2;

    // phase 1: online softmax stats over strided edges
    float m_l = -3.0e38f, s_l = 0.f;
    for (int i = start + grp; i < end; i += 16) {
        float v = bf2f(esort[(size_t)i * 4 + hh]);
        float mn = fmaxf(m_l, v);
        s_l = s_l * __expf(m_l - mn) + __expf(v - mn);
        m_l = mn;
    }
#pragma unroll
    for (int off = 4; off < 64; off <<= 1) {
        float mo = __shfl_xor(m_l, off), so = __shfl_xor(s_l, off);
        float mn = fmaxf(m_l, mo);
        s_l = s_l * __expf(m_l - mn) + so * __expf(mo - mn);
        m_l = mn;
    }
    const float inv_s = 1.0f / s_l;

    // phase 2
    const int g = lane >> 4;          // edge slot within quad-group
    const int q = lane & 15;          // dim quarter: dims q*8..q*8+7
    const int head2 = q >> 2;
    float4 accA = make_float4(0.f, 0.f, 0.f, 0.f);
    float4 accB = make_float4(0.f, 0.f, 0.f, 0.f);
    for (int chunk = start; chunk < end; chunk += 16) {
        float wv = 0.f; int si_l = 0;
        if (chunk + grp < end) {
            si_l = src_sorted[chunk + grp];
            float v = bf2f(esort[(size_t)(chunk + grp) * 4 + hh]);
            wv = __expf(v - m_l) * inv_s;
        }
#pragma unroll
        for (int t = 0; t < 4; t++) {
            int e_in = t * 4 + g;
            int si = __shfl(si_l, e_in * 4);
            float ww = __shfl(wv, e_in * 4 + head2);
            uint4 hv = *(const uint4*)&h[(size_t)si * 128 + q * 8];
            accA.x += ww * __uint_as_float(hv.x << 16);
            accA.y += ww * __uint_as_float(hv.x & 0xffff0000u);
            accA.z += ww * __uint_as_float(hv.y << 16);
            accA.w += ww * __uint_as_float(hv.y & 0xffff0000u);
            accB.x += ww * __uint_as_float(hv.z << 16);
            accB.y += ww * __uint_as_float(hv.z & 0xffff0000u);
            accB.z += ww * __uint_as_float(hv.w << 16);
            accB.w += ww * __uint_as_float(hv.w & 0xffff0000u);
        }
    }
    // combine the 4 edge slots (lane bits 4,5)
#pragma unroll
    for (int off = 16; off < 64; off <<= 1) {
        accA.x += __shfl_xor(accA.x, off); accA.y += __shfl_xor(accA.y, off);
        accA.z += __shfl_xor(accA.z, off); accA.w += __shfl_xor(accA.w, off);
        accB.x += __shfl_xor(accB.x, off); accB.y += __shfl_xor(accB.y, off);
        accB.z += __shfl_xor(accB.z, off); accB.w += __shfl_xor(accB.w, off);
    }
    if (lane < 16) {
        float4* o = (float4*)(out + (size_t)n * HD + lane * 8);
        float4 c0 = o[0], c1 = o[1];
        c0.x += accA.x; c0.y += accA.y; c0.z += accA.z; c0.w += accA.w;
        c1.x += accB.x; c1.y += accB.y; c1.z += accB.z; c1.w += accB.w;
        o[0] = c0; o[1] = c1;
    }
}

extern "C" void kernel_launch(void* const* d_in, const int* in_sizes, int n_in,
                              void* d_out, int out_size, void* d_ws, size_t ws_size,
                              hipStream_t stream) {
    const float* feat     = (const float*)d_in[0];
    const float* fc_w     = (const float*)d_in[1];
    const float* attn_src = (const float*)d_in[2];
    const float* attn_dst = (const float*)d_in[3];
    const int*   src      = (const int*)d_in[4];
    const int*   dst      = (const int*)d_in[5];
    const int N = in_sizes[0] / HD;
    const int E = in_sizes[4];
    float* out = (float*)d_out;

    // ws: h_bf16[N*128] | e_src[N*4] | e_dst[N*4] | ws_at[1024] | esort_bf16[E*4] |
    //     counts[N] | offsets[N+1] | cursor[N] | src_sorted[E] | bsum[1024]
    unsigned short* h = (unsigned short*)d_ws;
    float* e_src  = (float*)(h + (size_t)N * HD);
    float* e_dst  = e_src + (size_t)N * NHEADS;
    float* ws_at  = e_dst + (size_t)N * NHEADS;
    unsigned short* esort = (unsigned short*)(ws_at + 1024);
    int* counts     = (int*)(esort + (size_t)E * NHEADS);
    int* offsets    = counts + N;
    int* cursor     = offsets + (N + 1);
    int* src_sorted = cursor + N;
    int* bsum       = src_sorted + E;

    const int nb = (N + 1023) / 1024;   // blocks for scan passes (<=1024)

    zero_counts<<<(N + 255) / 256, 256, 0, stream>>>(counts, N);
    hist_dst<<<(E + 255) / 256, 256, 0, stream>>>(dst, counts, E);
    scan_pass1<<<nb, 256, 0, stream>>>(counts, bsum, N);
    scan_pass2<<<1, 1024, 0, stream>>>(bsum, nb);
    scan_pass3<<<nb, 256, 0, stream>>>(counts, bsum, offsets, cursor, N, E);
    make_ws<<<4, 256, 0, stream>>>(fc_w, attn_src, attn_dst, ws_at);
    logits<<<(N + 7) / 8, 256, 0, stream>>>(feat, ws_at, e_src, e_dst, N);
    scatter_edges<<<(E + 255) / 256, 256, 0, stream>>>(src, dst, cursor, src_sorted,
                                                       e_src, e_dst, esort, E);
    gemm_mfma<<<(N + MBLK - 1) / MBLK, 256, 0, stream>>>(feat, fc_w, h, out, N);
    node_agg<<<(N + 3) / 4, 256, 0, stream>>>(src_sorted, offsets, esort, h, out, N);
}

// Round 8
// 375.677 us; speedup vs baseline: 16.9530x; 1.1311x over previous
//
#include <hip/hip_runtime.h>

#define HD 128        // NUM_HEADS*OUT_DIM == IN_DIM
#define NHEADS 4
#define MBLK 128      // gemm rows per block
#define APITCH 136    // LDS pitch in ushorts

typedef __attribute__((ext_vector_type(8))) short bf16x8;
typedef __attribute__((ext_vector_type(4))) float f32x4;

__device__ __forceinline__ unsigned short f2bf(float x) {   // RNE
    union { float f; unsigned u; } a; a.f = x;
    unsigned r = a.u + 0x7fffu + ((a.u >> 16) & 1u);
    return (unsigned short)(r >> 16);
}
__device__ __forceinline__ float bf2f(unsigned short u) {
    return __uint_as_float(((unsigned)u) << 16);
}

// ---------------- sort pipeline ----------------
__global__ void zero_counts(int* __restrict__ counts, int N) {
    int i = blockIdx.x * blockDim.x + threadIdx.x;
    if (i < N) counts[i] = 0;
}
__global__ void hist_dst(const int* __restrict__ dst, int* __restrict__ counts, int E) {
    int e = blockIdx.x * blockDim.x + threadIdx.x;
    if (e < E) atomicAdd(&counts[dst[e]], 1);
}
__global__ __launch_bounds__(256) void scan_pass1(const int* __restrict__ counts,
                                                  int* __restrict__ bsum, int N) {
    __shared__ int wsum[4];
    int tid = threadIdx.x;
    int i0 = blockIdx.x * 1024 + tid * 4;
    int s = 0;
#pragma unroll
    for (int j = 0; j < 4; j++) s += (i0 + j < N) ? counts[i0 + j] : 0;
#pragma unroll
    for (int off = 1; off < 64; off <<= 1) s += __shfl_xor(s, off);
    if ((tid & 63) == 0) wsum[tid >> 6] = s;
    __syncthreads();
    if (tid == 0) bsum[blockIdx.x] = wsum[0] + wsum[1] + wsum[2] + wsum[3];
}
__global__ __launch_bounds__(1024) void scan_pass2(int* __restrict__ bsum, int nb) {
    __shared__ int sm[1024];
    int tid = threadIdx.x;
    int orig = (tid < nb) ? bsum[tid] : 0;
    sm[tid] = orig;
    __syncthreads();
    for (int off = 1; off < 1024; off <<= 1) {
        int v = (tid >= off) ? sm[tid - off] : 0;
        __syncthreads();
        sm[tid] += v;
        __syncthreads();
    }
    if (tid < nb) bsum[tid] = sm[tid] - orig;   // exclusive
}
__global__ __launch_bounds__(256) void scan_pass3(const int* __restrict__ counts,
        const int* __restrict__ bsum, int* __restrict__ offsets, int* __restrict__ cursor,
        int N, int E) {
    __shared__ int wsum[4];
    int tid = threadIdx.x, lane = tid & 63, wid = tid >> 6;
    int i0 = blockIdx.x * 1024 + tid * 4;
    int v[4];
#pragma unroll
    for (int j = 0; j < 4; j++) v[j] = (i0 + j < N) ? counts[i0 + j] : 0;
    int local = v[0] + v[1] + v[2] + v[3];
    int incl = local;
#pragma unroll
    for (int off = 1; off < 64; off <<= 1) {
        int t = __shfl_up(incl, off);
        if (lane >= off) incl += t;
    }
    if (lane == 63) wsum[wid] = incl;
    __syncthreads();
    int base = bsum[blockIdx.x];
    for (int w = 0; w < wid; w++) base += wsum[w];
    int excl = base + incl - local;
#pragma unroll
    for (int j = 0; j < 4; j++) {
        if (i0 + j < N) { offsets[i0 + j] = excl; cursor[i0 + j] = excl; }
        excl += v[j];
    }
    if (blockIdx.x == 0 && tid == 0) offsets[N] = E;
}

// scatter: ONE 16B record per edge = {src, pad, l0|l1, l2|l3}
// -> logits occupy ushorts 4..7 of the record, matching node_agg's ep[i*8+4+hh] read.
__global__ void scatter_edges(const int* __restrict__ src, const int* __restrict__ dst,
                              int* __restrict__ cursor,
                              const float* __restrict__ e_src, const float* __restrict__ e_dst,
                              uint4* __restrict__ erec, int E) {
    int e = blockIdx.x * blockDim.x + threadIdx.x;
    if (e >= E) return;
    int si = src[e], di = dst[e];
    int pos = atomicAdd(&cursor[di], 1);
    float4 es = ((const float4*)e_src)[si];
    float4 ed = ((const float4*)e_dst)[di];
    float v0 = es.x + ed.x; v0 = v0 > 0.f ? v0 : 0.2f * v0;
    float v1 = es.y + ed.y; v1 = v1 > 0.f ? v1 : 0.2f * v1;
    float v2 = es.z + ed.z; v2 = v2 > 0.f ? v2 : 0.2f * v2;
    float v3 = es.w + ed.w; v3 = v3 > 0.f ? v3 : 0.2f * v3;
    uint4 r;
    r.x = (unsigned)si;
    r.y = 0u;                                                  // pad
    r.z = (unsigned)f2bf(v0) | ((unsigned)f2bf(v1) << 16);     // ushorts 4,5
    r.w = (unsigned)f2bf(v2) | ((unsigned)f2bf(v3) << 16);     // ushorts 6,7
    erec[pos] = r;
}

// ---------------- logits from bf16 h (runs after gemm): 32 lanes/node ----------------
__global__ __launch_bounds__(256) void logits(
    const unsigned short* __restrict__ h,
    const float* __restrict__ attn_src, const float* __restrict__ attn_dst,
    float* __restrict__ e_src, float* __restrict__ e_dst, int N)
{
    int widx = (blockIdx.x * 256 + threadIdx.x) >> 6;
    int lane = threadIdx.x & 63;
    int sub = lane >> 5, sl = lane & 31;
    int n = widx * 2 + sub;
    if (n >= N) return;
    uint2 hv = ((const uint2*)h)[(size_t)n * 32 + sl];       // dims sl*4..sl*4+3
    float4 as = ((const float4*)attn_src)[sl];
    float4 ad = ((const float4*)attn_dst)[sl];
    float x0 = __uint_as_float(hv.x << 16);
    float x1 = __uint_as_float(hv.x & 0xffff0000u);
    float x2 = __uint_as_float(hv.y << 16);
    float x3 = __uint_as_float(hv.y & 0xffff0000u);
    float ps = x0 * as.x + x1 * as.y + x2 * as.z + x3 * as.w;
    float pd = x0 * ad.x + x1 * ad.y + x2 * ad.z + x3 * ad.w;
    // reduce over the 8 lanes of each head (sl = head*8 + j)
    ps += __shfl_xor(ps, 1); ps += __shfl_xor(ps, 2); ps += __shfl_xor(ps, 4);
    pd += __shfl_xor(pd, 1); pd += __shfl_xor(pd, 2); pd += __shfl_xor(pd, 4);
    if ((sl & 7) == 0) {
        int head = sl >> 3;
        e_src[n * 4 + head] = ps;
        e_dst[n * 4 + head] = pd;
    }
}

// ---------------- bf16 MFMA GEMM: h = feat @ fc_w.T (bf16 out), fused residual init ----------------
__global__ __launch_bounds__(256, 2) void gemm_mfma(
    const float* __restrict__ feat, const float* __restrict__ fc_w,
    unsigned short* __restrict__ h, float* __restrict__ out, int N)
{
    __shared__ unsigned short As[MBLK * APITCH];
    __shared__ unsigned short Bs[HD * APITCH];
    const int tid = threadIdx.x;
    const int row0 = blockIdx.x * MBLK;

    for (int i = tid; i < 128 * 32; i += 256) {
        int o = i >> 5, j = i & 31;
        float4 v = ((const float4*)fc_w)[i];
        ushort4 u; u.x = f2bf(v.x); u.y = f2bf(v.y); u.z = f2bf(v.z); u.w = f2bf(v.w);
        *(ushort4*)&Bs[o * APITCH + j * 4] = u;
    }
    for (int i = tid; i < MBLK * 32; i += 256) {
        int r = i >> 5, j = i & 31;
        int rowg = row0 + r;
        float4 v = make_float4(0.f, 0.f, 0.f, 0.f);
        if (rowg < N) {
            v = ((const float4*)feat)[(size_t)rowg * 32 + j];
            ((float4*)out)[(size_t)rowg * 32 + j] = v;   // residual init
        }
        ushort4 u; u.x = f2bf(v.x); u.y = f2bf(v.y); u.z = f2bf(v.z); u.w = f2bf(v.w);
        *(ushort4*)&As[r * APITCH + j * 4] = u;
    }
    __syncthreads();

    const int w = tid >> 6, lane = tid & 63, quad = lane >> 4, lr = lane & 15;
    f32x4 acc[2][8];
#pragma unroll
    for (int rt = 0; rt < 2; rt++)
#pragma unroll
        for (int ct = 0; ct < 8; ct++) acc[rt][ct] = (f32x4){0.f, 0.f, 0.f, 0.f};

#pragma unroll
    for (int ks = 0; ks < 4; ks++) {
        const int k0 = ks * 32 + quad * 8;
        bf16x8 a0 = *(const bf16x8*)&As[(w * 32 + lr) * APITCH + k0];
        bf16x8 a1 = *(const bf16x8*)&As[(w * 32 + 16 + lr) * APITCH + k0];
        bf16x8 bf[8];
#pragma unroll
        for (int ct = 0; ct < 8; ct++)
            bf[ct] = *(const bf16x8*)&Bs[(ct * 16 + lr) * APITCH + k0];
#pragma unroll
        for (int ct = 0; ct < 8; ct++) {
            acc[0][ct] = __builtin_amdgcn_mfma_f32_16x16x32_bf16(a0, bf[ct], acc[0][ct], 0, 0, 0);
            acc[1][ct] = __builtin_amdgcn_mfma_f32_16x16x32_bf16(a1, bf[ct], acc[1][ct], 0, 0, 0);
        }
    }
#pragma unroll
    for (int rt = 0; rt < 2; rt++) {
#pragma unroll
        for (int ct = 0; ct < 8; ct++) {
            int col = ct * 16 + lr;
#pragma unroll
            for (int reg = 0; reg < 4; reg++) {
                int row = row0 + w * 32 + rt * 16 + quad * 4 + reg;
                if (row < N) h[(size_t)row * 128 + col] = f2bf(acc[rt][ct][reg]);
            }
        }
    }
}

// ---------------- per-node fused softmax + aggregation (packed 16B records) ----------------
__global__ __launch_bounds__(256) void node_agg(
    const uint4* __restrict__ erec, const int* __restrict__ offsets,
    const unsigned short* __restrict__ h, float* __restrict__ out, int N)
{
    int n = (blockIdx.x * 256 + threadIdx.x) >> 6;
    int lane = threadIdx.x & 63;
    if (n >= N) return;
    int start = offsets[n], end = offsets[n + 1];
    if (start == end) return;                     // residual only

    const unsigned short* ep = (const unsigned short*)erec;   // record i: src at dword i*4; logits at ushorts i*8+4..7
    const int* ei = (const int*)erec;

    const int hh = lane & 3;
    const int grp = lane >> 2;

    // phase 1: online softmax stats (lane = grp*4+hh)
    float m_l = -3.0e38f, s_l = 0.f;
    for (int i = start + grp; i < end; i += 16) {
        float v = bf2f(ep[(size_t)i * 8 + 4 + hh]);
        float mn = fmaxf(m_l, v);
        s_l = s_l * __expf(m_l - mn) + __expf(v - mn);
        m_l = mn;
    }
#pragma unroll
    for (int off = 4; off < 64; off <<= 1) {
        float mo = __shfl_xor(m_l, off), so = __shfl_xor(s_l, off);
        float mn = fmaxf(m_l, mo);
        s_l = s_l * __expf(m_l - mn) + so * __expf(mo - mn);
        m_l = mn;
    }
    const float inv_s = 1.0f / s_l;

    // phase 2: 4 edges in flight x 16 lanes x 16B h loads
    const int g = lane >> 4;
    const int q = lane & 15;
    const int head2 = q >> 2;
    float4 accA = make_float4(0.f, 0.f, 0.f, 0.f);
    float4 accB = make_float4(0.f, 0.f, 0.f, 0.f);
    for (int chunk = start; chunk < end; chunk += 16) {
        float wv = 0.f; int si_l = 0;
        if (chunk + grp < end) {
            si_l = ei[(size_t)(chunk + grp) * 4];
            float v = bf2f(ep[(size_t)(chunk + grp) * 8 + 4 + hh]);
            wv = __expf(v - m_l) * inv_s;
        }
#pragma unroll
        for (int t = 0; t < 4; t++) {
            int e_in = t * 4 + g;
            int si = __shfl(si_l, e_in * 4);
            float ww = __shfl(wv, e_in * 4 + head2);
            uint4 hv = *(const uint4*)&h[(size_t)si * 128 + q * 8];
            accA.x += ww * __uint_as_float(hv.x << 16);
            accA.y += ww * __uint_as_float(hv.x & 0xffff0000u);
            accA.z += ww * __uint_as_float(hv.y << 16);
            accA.w += ww * __uint_as_float(hv.y & 0xffff0000u);
            accB.x += ww * __uint_as_float(hv.z << 16);
            accB.y += ww * __uint_as_float(hv.z & 0xffff0000u);
            accB.z += ww * __uint_as_float(hv.w << 16);
            accB.w += ww * __uint_as_float(hv.w & 0xffff0000u);
        }
    }
#pragma unroll
    for (int off = 16; off < 64; off <<= 1) {
        accA.x += __shfl_xor(accA.x, off); accA.y += __shfl_xor(accA.y, off);
        accA.z += __shfl_xor(accA.z, off); accA.w += __shfl_xor(accA.w, off);
        accB.x += __shfl_xor(accB.x, off); accB.y += __shfl_xor(accB.y, off);
        accB.z += __shfl_xor(accB.z, off); accB.w += __shfl_xor(accB.w, off);
    }
    if (lane < 16) {
        float4* o = (float4*)(out + (size_t)n * HD + lane * 8);
        float4 c0 = o[0], c1 = o[1];
        c0.x += accA.x; c0.y += accA.y; c0.z += accA.z; c0.w += accA.w;
        c1.x += accB.x; c1.y += accB.y; c1.z += accB.z; c1.w += accB.w;
        o[0] = c0; o[1] = c1;
    }
}

extern "C" void kernel_launch(void* const* d_in, const int* in_sizes, int n_in,
                              void* d_out, int out_size, void* d_ws, size_t ws_size,
                              hipStream_t stream) {
    const float* feat     = (const float*)d_in[0];
    const float* fc_w     = (const float*)d_in[1];
    const float* attn_src = (const float*)d_in[2];
    const float* attn_dst = (const float*)d_in[3];
    const int*   src      = (const int*)d_in[4];
    const int*   dst      = (const int*)d_in[5];
    const int N = in_sizes[0] / HD;
    const int E = in_sizes[4];
    float* out = (float*)d_out;

    // ws: h_bf16[N*128] | e_src[N*4] | e_dst[N*4] | erec[E] uint4 | counts[N] | offsets[N+1] | cursor[N] | bsum[1024]
    unsigned short* h = (unsigned short*)d_ws;
    float* e_src  = (float*)(h + (size_t)N * HD);
    float* e_dst  = e_src + (size_t)N * NHEADS;
    uint4* erec   = (uint4*)(e_dst + (size_t)N * NHEADS);
    int* counts   = (int*)(erec + (size_t)E);
    int* offsets  = counts + N;
    int* cursor   = offsets + (N + 1);
    int* bsum     = cursor + N;

    const int nb = (N + 1023) / 1024;

    zero_counts<<<(N + 255) / 256, 256, 0, stream>>>(counts, N);
    hist_dst<<<(E + 255) / 256, 256, 0, stream>>>(dst, counts, E);
    scan_pass1<<<nb, 256, 0, stream>>>(counts, bsum, N);
    scan_pass2<<<1, 1024, 0, stream>>>(bsum, nb);
    scan_pass3<<<nb, 256, 0, stream>>>(counts, bsum, offsets, cursor, N, E);
    gemm_mfma<<<(N + MBLK - 1) / MBLK, 256, 0, stream>>>(feat, fc_w, h, out, N);
    logits<<<(N + 7) / 8, 256, 0, stream>>>(h, attn_src, attn_dst, e_src, e_dst, N);
    scatter_edges<<<(E + 255) / 256, 256, 0, stream>>>(src, dst, cursor, e_src, e_dst, erec, E);
    node_agg<<<(N + 3) / 4, 256, 0, stream>>>(erec, offsets, h, out, N);
}